// Round 9
// baseline (1462.979 us; speedup 1.0000x reference)
//
#include <hip/hip_runtime.h>

// Problem constants (fixed by the reference).
#define BS 64
#define DX 512
#define DY 512
#define L (DX * DY)                 // 262144 bins per sample
#define TILE 1024                   // elements per tile (= THREADS * EPT)
#define T_PER_S (L / TILE)          // 256 tiles per sample
#define THREADS 256
#define EPT 4                       // one float4 per thread
#define NTILES (BS * T_PER_S)       // 16384

typedef float vfloat2 __attribute__((ext_vector_type(2)));
typedef float vfloat4 __attribute__((ext_vector_type(4)));

#define ST_AGG 1ull
#define ST_PRE 2ull

// ---------------------------------------------------------------------------
// Single-pass compaction with decoupled lookback (per-sample chains).
// Per tile: block-scan counts -> publish (AGG,total) -> wave0 lookback for
// the exclusive same-sample prefix 'off' -> publish (PRE, off+total) ->
// 16B-packed LDS-staged stream-out (R8-verified) -> tail-zero the range
// [L - t*TILE + off - (TILE-total), L - t*TILE + off), whose union over the
// sample's tiles is exactly [len, L). lens[b] written by tile t==255.
// Harness poisons ws with 0xAA -> status nibble is neither 1 nor 2 ->
// lookback treats it as not-ready; no init dispatch required.
// ---------------------------------------------------------------------------
__global__ __launch_bounds__(THREADS) void htpc_onepass(
    const float* __restrict__ hist, const float* __restrict__ x_lims,
    const float* __restrict__ y_lims, unsigned long long* __restrict__ state,
    float* __restrict__ out_pc, float* __restrict__ out_w,
    float* __restrict__ out_lens) {
  __shared__ int sidx[TILE];        // 4 KiB
  __shared__ float sw[TILE];        // 4 KiB
  __shared__ int wsum[THREADS / 64];
  __shared__ int s_off;

  const int g = blockIdx.x;
  const int b = g >> 8;        // sample
  const int t = g & 255;       // tile within sample
  const int tid = threadIdx.x;
  const int lane = tid & 63;
  const int wv = tid >> 6;

  // own float4 (chunk == vector: coalesced AND thread-contiguous => stable)
  const float4 a = ((const float4*)(hist + (size_t)g * TILE))[tid];
  float v[EPT] = {a.x, a.y, a.z, a.w};
  int cnt = (v[0] != 0.f) + (v[1] != 0.f) + (v[2] != 0.f) + (v[3] != 0.f);

  // block exclusive scan over 256 thread counts
  int incl = cnt;
#pragma unroll
  for (int d = 1; d < 64; d <<= 1) {
    int n = __shfl_up(incl, d);
    if (lane >= d) incl += n;
  }
  if (lane == 63) wsum[wv] = incl;
  __syncthreads();
  int wbase = 0, total = 0;
#pragma unroll
  for (int i = 0; i < THREADS / 64; ++i) {
    int s = wsum[i];
    if (i < wv) wbase += s;
    total += s;
  }
  int r = wbase + (incl - cnt);  // stable rank within tile

  // publish aggregate ASAP (t==0 publishes its inclusive prefix directly)
  if (tid == 0) {
    const unsigned long long pub =
        ((t == 0 ? ST_PRE : ST_AGG) << 32) | (unsigned)total;
    __hip_atomic_store(&state[g], pub, __ATOMIC_RELEASE,
                       __HIP_MEMORY_SCOPE_AGENT);
  }

  // stage (idx, w) at stable ranks (overlaps with wave0's lookback below)
  const int lidx0 = t * TILE + tid * EPT;  // index within sample
#pragma unroll
  for (int i = 0; i < EPT; ++i) {
    if (v[i] != 0.f) {
      sidx[r] = lidx0 + i;
      sw[r] = v[i];
      ++r;
    }
  }

  // wave0: decoupled lookback over same-sample predecessors, 64-wide windows
  if (wv == 0) {
    unsigned off = 0;
    int remaining = t;
    int dist = 1;
    while (remaining > 0) {
      const int chunk = remaining < 64 ? remaining : 64;
      unsigned long long s = 0;
      if (lane < chunk) {
        unsigned st;
        do {
          s = __hip_atomic_load(&state[g - dist - lane], __ATOMIC_ACQUIRE,
                                __HIP_MEMORY_SCOPE_AGENT);
          st = (unsigned)(s >> 32);
        } while (st != 1u && st != 2u);
      }
      const unsigned stt = (unsigned)(s >> 32);
      const unsigned vv = (unsigned)s;
      const unsigned long long m = __ballot(lane < chunk && stt == 2u);
      unsigned contrib;
      if (m) {
        const int j = __ffsll((unsigned long long)m) - 1;  // nearest PRE
        contrib = (lane <= j) ? vv : 0;  // aggs before + inclusive at j
        remaining = 0;
      } else {
        contrib = (lane < chunk) ? vv : 0;
        remaining -= chunk;
        dist += chunk;
      }
#pragma unroll
      for (int d = 32; d > 0; d >>= 1) contrib += __shfl_down(contrib, d);
      off += __shfl(contrib, 0);
    }
    if (lane == 0) {
      s_off = (int)off;
      if (t > 0) {
        const unsigned long long pub = (ST_PRE << 32) | (off + (unsigned)total);
        __hip_atomic_store(&state[g], pub, __ATOMIC_RELEASE,
                           __HIP_MEMORY_SCOPE_AGENT);
      }
      if (t == 255) out_lens[b] = (float)(off + (unsigned)total);
    }
  }
  __syncthreads();  // s_off + staging ready
  const int off = s_off;

  // center-grid params: cx[j] = xlo + cxw*(j+0.5)
  const float xlo = x_lims[b * 2], xhi = x_lims[b * 2 + 1];
  const float ylo = y_lims[b * 2], yhi = y_lims[b * 2 + 1];
  const float cxw = (xhi - xlo) / DX;
  const float cyw = (yhi - ylo) / DY;

  vfloat2* pc2 = (vfloat2*)out_pc + (size_t)b * L;  // pair units
  float* w = out_w + (size_t)b * L;

  if (total > 0) {
    // ---- pc pairs: head (odd off), dwordx4 body (2 pairs), odd tail ----
    const int ho = off & 1;
    if (ho && tid == 0) {
      const int idx = sidx[0];
      vfloat2 p;
      p.x = xlo + cxw * ((float)(idx >> 9) + 0.5f);
      p.y = ylo + cyw * ((float)(idx & 511) + 0.5f);
      pc2[off] = p;
    }
    const int remp = total - ho;
    const int nb = remp >> 1;
    for (int k = tid; k < nb; k += THREADS) {
      const int s = ho + 2 * k;
      const int i0 = sidx[s], i1 = sidx[s + 1];
      vfloat4 q;
      q.x = xlo + cxw * ((float)(i0 >> 9) + 0.5f);
      q.y = ylo + cyw * ((float)(i0 & 511) + 0.5f);
      q.z = xlo + cxw * ((float)(i1 >> 9) + 0.5f);
      q.w = ylo + cyw * ((float)(i1 & 511) + 0.5f);
      __builtin_nontemporal_store(q, (vfloat4*)(pc2 + off + s));
    }
    if ((remp & 1) && tid == 0) {
      const int s = ho + 2 * nb;
      const int idx = sidx[s];
      vfloat2 p;
      p.x = xlo + cxw * ((float)(idx >> 9) + 0.5f);
      p.y = ylo + cyw * ((float)(idx & 511) + 0.5f);
      pc2[off + s] = p;
    }

    // ---- w: scalar head to 16B alignment, dwordx4 body, scalar tail ----
    const int hw0 = (4 - (off & 3)) & 3;
    const int hw = hw0 < total ? hw0 : total;
    if (tid < hw) w[off + tid] = sw[tid];
    const int remw = total - hw;
    const int nw = remw >> 2;
    const float* swb = sw + hw;
    float* wb = w + off + hw;
    for (int k = tid; k < nw; k += THREADS) {
      vfloat4 q;
      q.x = swb[4 * k + 0];
      q.y = swb[4 * k + 1];
      q.z = swb[4 * k + 2];
      q.w = swb[4 * k + 3];
      __builtin_nontemporal_store(q, (vfloat4*)wb + k);
    }
    const int tw = remw & 3;
    if (tid < tw) wb[4 * nw + tid] = swb[4 * nw + tid];
  }

  // tail-zero: this tile's slack z = TILE-total maps to
  // [L - zoff - z, L - zoff), zoff = t*TILE - off; union over tiles = [len,L).
  const int zhi = L - t * TILE + off;
  const int zlo = zhi - (TILE - total);
  if (zlo < zhi) {
    // pc pairs (8 B units): even-align head, 16B body, odd tail
    int a0 = zlo;
    if (a0 & 1) {
      if (tid == 0) {
        const vfloat2 z2 = {0.f, 0.f};
        __builtin_nontemporal_store(z2, pc2 + a0);
      }
      ++a0;
    }
    if (a0 < zhi) {
      const int n4 = (zhi - a0) >> 1;
      const vfloat4 z4 = {0.f, 0.f, 0.f, 0.f};
      vfloat4* p4 = (vfloat4*)(pc2 + a0);
      for (int k = tid; k < n4; k += THREADS)
        __builtin_nontemporal_store(z4, p4 + k);
      if ((zhi - a0) & 1) {
        if (tid == 0) {
          const vfloat2 z2 = {0.f, 0.f};
          __builtin_nontemporal_store(z2, pc2 + zhi - 1);
        }
      }
    }
    // w floats (4 B units): head to 16B, body, tail
    int h = (4 - (zlo & 3)) & 3;
    if (h > zhi - zlo) h = zhi - zlo;
    if (tid < h) __builtin_nontemporal_store(0.f, w + zlo + tid);
    const int b0 = zlo + h;
    if (b0 < zhi) {
      const int n4 = (zhi - b0) >> 2;
      const vfloat4 z4 = {0.f, 0.f, 0.f, 0.f};
      vfloat4* w4 = (vfloat4*)(w + b0);
      for (int k = tid; k < n4; k += THREADS)
        __builtin_nontemporal_store(z4, w4 + k);
      const int rem = (zhi - b0) & 3;
      if (tid < rem)
        __builtin_nontemporal_store(0.f, w + b0 + 4 * n4 + tid);
    }
  }
}

extern "C" void kernel_launch(void* const* d_in, const int* in_sizes, int n_in,
                              void* d_out, int out_size, void* d_ws,
                              size_t ws_size, hipStream_t stream) {
  const float* hist = (const float*)d_in[0];    // [BS, DX, DY]
  const float* x_lims = (const float*)d_in[1];  // [BS, 2]
  const float* y_lims = (const float*)d_in[2];  // [BS, 2]

  float* out = (float*)d_out;
  float* out_pc = out;                          // [BS, L, 2]
  float* out_w = out + (size_t)BS * L * 2;      // [BS, L]
  float* out_lens = out_w + (size_t)BS * L;     // [BS] (as float32)

  unsigned long long* state = (unsigned long long*)d_ws;  // [NTILES] = 128 KiB

  htpc_onepass<<<NTILES, THREADS, 0, stream>>>(
      hist, x_lims, y_lims, state, out_pc, out_w, out_lens);
}

// Round 10
// 255.437 us; speedup vs baseline: 5.7274x; 5.7274x over previous
//
#include <hip/hip_runtime.h>

// Problem constants (fixed by the reference).
#define BS 64
#define DX 512
#define DY 512
#define L (DX * DY)                 // 262144 bins per sample
#define TILE 1024                   // elements per tile (= THREADS * EPT)
#define T_PER_S (L / TILE)          // 256 tiles per sample
#define THREADS 256
#define EPT 4                       // one float4 per thread: chunk == vector
#define NTILES (BS * T_PER_S)       // 16384

typedef float vfloat2 __attribute__((ext_vector_type(2)));
typedef float vfloat4 __attribute__((ext_vector_type(4)));

// ---------------------------------------------------------------------------
// R10 = exact revert to R8 (session best: 255.8 us).
// R5 (cooperative grid.sync) and R9 (decoupled lookback) both proved that
// cross-block synchronization on this chip costs far more than the 11 us
// count pass it would eliminate (per-XCD L2 non-coherence => agent-scope
// spin traffic saturates the interconnect). Two plain dispatches win.
// ---------------------------------------------------------------------------

// Phase 1: per-tile nonzero counts. One float4 per thread, lane-consecutive
// (fully coalesced: 16 lines/instr, 4 lanes/line).
__global__ __launch_bounds__(THREADS) void htpc_count(
    const float* __restrict__ hist, int* __restrict__ tile_count) {
  const int tile = blockIdx.x;
  const float4 a = ((const float4*)(hist + (size_t)tile * TILE))[threadIdx.x];
  int cnt = (a.x != 0.f) + (a.y != 0.f) + (a.z != 0.f) + (a.w != 0.f);

  const int lane = threadIdx.x & 63;
  const int wv = threadIdx.x >> 6;
#pragma unroll
  for (int d = 32; d > 0; d >>= 1) cnt += __shfl_down(cnt, d);
  __shared__ int ws[THREADS / 64];
  if (lane == 0) ws[wv] = cnt;
  __syncthreads();
  if (threadIdx.x == 0)
    tile_count[tile] = ws[0] + ws[1] + ws[2] + ws[3];
}

// Phase 2: fused scan + compact + tail-zero, one block per 1024-elem tile.
// Per-thread chunk = one float4 => hist load is lane-consecutive AND
// thread-contiguous (stable ranks, zero transaction inflation).
// The per-sample tile-offset scan (256 entries, thread i <-> tile i) and the
// per-thread rank scan are fused into ONE packed 64-bit block scan:
//   val = (tile_count << 32) | own_cnt   (sums fit: <=262144 / <=1024).
__global__ __launch_bounds__(THREADS) void htpc_fused(
    const float* __restrict__ hist, const float* __restrict__ x_lims,
    const float* __restrict__ y_lims, const int* __restrict__ tile_count,
    float* __restrict__ out_pc, float* __restrict__ out_w,
    float* __restrict__ out_lens) {
  __shared__ int sidx[TILE];                       // 4 KiB
  __shared__ float sw[TILE];                       // 4 KiB
  __shared__ unsigned long long wsum[THREADS / 64];
  __shared__ int s_off_mine;

  const int g = blockIdx.x;
  const int b = g >> 8;        // sample
  const int t = g & 255;       // tile within sample
  const int tid = threadIdx.x;

  // own float4 (chunk == vector)
  const float4 a = ((const float4*)(hist + (size_t)g * TILE))[tid];
  float v[EPT] = {a.x, a.y, a.z, a.w};
  int cnt = (v[0] != 0.f) + (v[1] != 0.f) + (v[2] != 0.f) + (v[3] != 0.f);

  // tile count for the sample-wide offset scan (thread i <-> tile i)
  const int c_tile = tile_count[b * T_PER_S + tid];

  // packed 64-bit block inclusive scan over 256 threads
  const int lane = tid & 63;
  const int wv = tid >> 6;
  unsigned long long val =
      ((unsigned long long)(unsigned)c_tile << 32) | (unsigned)cnt;
  unsigned long long incl = val;
#pragma unroll
  for (int d = 1; d < 64; d <<= 1) {
    unsigned long long n = __shfl_up(incl, d);
    if (lane >= d) incl += n;
  }
  if (lane == 63) wsum[wv] = incl;
  __syncthreads();
  unsigned long long wbase = 0, total = 0;
#pragma unroll
  for (int i = 0; i < THREADS / 64; ++i) {
    unsigned long long s = wsum[i];
    if (i < wv) wbase += s;
    total += s;
  }
  const unsigned long long ex = wbase + incl - val;  // exclusive prefix @tid
  int r = (int)(ex & 0xffffffffu);              // stable rank within tile
  const int offpref = (int)(ex >> 32);          // tile-offset prefix @tid
  const int len = (int)(total >> 32);           // sample nonzero count
  const int total_cnt = (int)(total & 0xffffffffu);  // nonzeros in this tile

  if (tid == t) s_off_mine = offpref;           // broadcast our tile's offset
  if (t == 0 && tid == 0) out_lens[b] = (float)len;

  // stage (idx, w) at stable ranks
  const int lidx0 = t * TILE + tid * EPT;       // index within sample
#pragma unroll
  for (int i = 0; i < EPT; ++i) {
    if (v[i] != 0.f) {
      sidx[r] = lidx0 + i;
      sw[r] = v[i];
      ++r;
    }
  }
  __syncthreads();  // staging + s_off_mine ready
  const int off = s_off_mine;

  // center-grid params: cx[j] = xlo + cxw*(j+0.5)
  const float xlo = x_lims[b * 2], xhi = x_lims[b * 2 + 1];
  const float ylo = y_lims[b * 2], yhi = y_lims[b * 2 + 1];
  const float cxw = (xhi - xlo) / DX;
  const float cyw = (yhi - ylo) / DY;

  vfloat2* pc2 = (vfloat2*)out_pc + (size_t)b * L;  // pair units
  float* w = out_w + (size_t)b * L;

  if (total_cnt > 0) {
    // ---- pc pairs: head (odd off), dwordx4 body (2 pairs), odd tail ----
    const int ho = off & 1;
    if (ho && tid == 0) {
      const int idx = sidx[0];
      vfloat2 p;
      p.x = xlo + cxw * ((float)(idx >> 9) + 0.5f);
      p.y = ylo + cyw * ((float)(idx & 511) + 0.5f);
      pc2[off] = p;
    }
    const int remp = total_cnt - ho;
    const int nb = remp >> 1;
    for (int k = tid; k < nb; k += THREADS) {
      const int s = ho + 2 * k;
      const int i0 = sidx[s], i1 = sidx[s + 1];
      vfloat4 q;
      q.x = xlo + cxw * ((float)(i0 >> 9) + 0.5f);
      q.y = ylo + cyw * ((float)(i0 & 511) + 0.5f);
      q.z = xlo + cxw * ((float)(i1 >> 9) + 0.5f);
      q.w = ylo + cyw * ((float)(i1 & 511) + 0.5f);
      __builtin_nontemporal_store(q, (vfloat4*)(pc2 + off + s));
    }
    if ((remp & 1) && tid == 0) {
      const int s = ho + 2 * nb;
      const int idx = sidx[s];
      vfloat2 p;
      p.x = xlo + cxw * ((float)(idx >> 9) + 0.5f);
      p.y = ylo + cyw * ((float)(idx & 511) + 0.5f);
      pc2[off + s] = p;
    }

    // ---- w: scalar head to 16B alignment, dwordx4 body, scalar tail ----
    const int hw0 = (4 - (off & 3)) & 3;
    const int hw = hw0 < total_cnt ? hw0 : total_cnt;
    if (tid < hw) w[off + tid] = sw[tid];
    const int remw = total_cnt - hw;
    const int nw = remw >> 2;
    const float* swb = sw + hw;
    float* wb = w + off + hw;
    for (int k = tid; k < nw; k += THREADS) {
      vfloat4 q;
      q.x = swb[4 * k + 0];
      q.y = swb[4 * k + 1];
      q.z = swb[4 * k + 2];
      q.w = swb[4 * k + 3];
      __builtin_nontemporal_store(q, (vfloat4*)wb + k);
    }
    const int tw = remw & 3;
    if (tid < tw) wb[4 * nw + tid] = swb[4 * nw + tid];
  }

  // tail-zero this tile's output stripe ∩ [len, L), 16B NT stores (verified)
  const int begin = t * TILE;
  const int end = begin + TILE;
  int s0 = (len > begin) ? len : begin;
  if (s0 < end) {
    int a0 = s0;
    if (a0 & 1) {
      if (tid == 0) {
        const vfloat2 z2 = {0.f, 0.f};
        __builtin_nontemporal_store(z2, pc2 + a0);
      }
      ++a0;
    }
    {
      vfloat4* p4 = (vfloat4*)(pc2 + a0);
      const int n4 = (end - a0) >> 1;
      const vfloat4 z4 = {0.f, 0.f, 0.f, 0.f};
      for (int k = tid; k < n4; k += THREADS)
        __builtin_nontemporal_store(z4, p4 + k);
    }
    const int head = (s0 + 3) & ~3;
    if (tid < (head - s0) && (s0 + tid) < end)
      __builtin_nontemporal_store(0.f, w + s0 + tid);
    if (head < end) {
      vfloat4* w4 = (vfloat4*)(w + head);
      const int n4 = (end - head) >> 2;
      const vfloat4 z4 = {0.f, 0.f, 0.f, 0.f};
      for (int k = tid; k < n4; k += THREADS)
        __builtin_nontemporal_store(z4, w4 + k);
    }
  }
}

extern "C" void kernel_launch(void* const* d_in, const int* in_sizes, int n_in,
                              void* d_out, int out_size, void* d_ws,
                              size_t ws_size, hipStream_t stream) {
  const float* hist = (const float*)d_in[0];    // [BS, DX, DY]
  const float* x_lims = (const float*)d_in[1];  // [BS, 2]
  const float* y_lims = (const float*)d_in[2];  // [BS, 2]

  float* out = (float*)d_out;
  float* out_pc = out;                          // [BS, L, 2]
  float* out_w = out + (size_t)BS * L * 2;      // [BS, L]
  float* out_lens = out_w + (size_t)BS * L;     // [BS] (as float32)

  int* tile_count = (int*)d_ws;                 // [NTILES]

  htpc_count<<<NTILES, THREADS, 0, stream>>>(hist, tile_count);
  htpc_fused<<<NTILES, THREADS, 0, stream>>>(
      hist, x_lims, y_lims, tile_count, out_pc, out_w, out_lens);
}